// Round 5
// baseline (16850.026 us; speedup 1.0000x reference)
//
#include <hip/hip_runtime.h>
#include <math.h>

// LSTM: B=128, T=256, D=256, H=1024, C=10
// Round 6: persistent kernel — defeat load rematerialization + lean barrier.
//   Round-5 post-mortem: VGPR STILL 116 and no scratch traffic in the
//   counters (WRITE 67.5MB == hout exactly; FETCH 336MB == h/x refetch).
//   So the weights never spilled — the compiler SINKS the 40 loop-invariant
//   global loads into the K-loop (remat to cut pressure). Every wave
//   re-streams 40KB/step from L2 -> ~3us/step + barrier ~8us = 14.5us/step.
//   Fixes:
//   - asm("" : "+v"(w)) pins each named weight vector: value now originates
//     from an opaque asm, remat impossible -> 160 VGPRs stay live.
//   - Per-WAVE barrier arrival (RELEASE fetch_add by lane0; vmcnt drain is
//     wave-granular so it covers all 64 lanes' h stores), ALL waves
//     ACQUIRE-poll. Spin subsumes the block-local barrier -> 3 syncthreads
//     per step instead of 5, no tid0 broadcast hop.
//   - 1-D grid, by = id&7: round-robin dispatch (id%8=XCD) puts each row
//     group on ONE XCD -> h exchange intra-L2. Correctness does NOT depend
//     on placement (agent-scope atomics either way); it only buys speed.
// Workspace layout:
//   [0)          Wpack  bf16  10,485,760 B
//   [10485760)   xT     bf16  16,777,216 B   ([T][B][D], x transposed+cast)
//   [27262976)   h0     bf16     262,144 B
//   [27525120)   h1     bf16     262,144 B
//   [27787264)   barCnt u32        1,024 B   (8 groups x 128B stride)

#define BB 128
#define TT 256
#define DD 256
#define HH 1024
#define NKT 40   // 1280 / 32 k-tiles
#define KHT 20   // k-tiles per K-half wave

typedef __bf16 bf16x8 __attribute__((ext_vector_type(8)));
typedef float  f32x4  __attribute__((ext_vector_type(4)));
typedef unsigned short u16;
typedef u16 u16x8 __attribute__((ext_vector_type(8)));

__device__ __forceinline__ u16 f2bf(float f){
  unsigned u = __builtin_bit_cast(unsigned, f);
  u += 0x7fffu + ((u >> 16) & 1u);            // round-to-nearest-even
  return (u16)(u >> 16);
}
__device__ __forceinline__ float bf2f(u16 b){
  unsigned u = ((unsigned)b) << 16;
  return __builtin_bit_cast(float, u);
}
__device__ __forceinline__ float sigm(float x){
  return 1.f / (1.f + __expf(-x));
}
__device__ __forceinline__ float tanh_fast(float x){
  return 2.f / (1.f + __expf(-2.f * x)) - 1.f;
}
// LDS A-tile swizzle: breaks the staging-write 64-way bank conflict.
// slot bits: m=[0:3], q=[4:5], kt=[6:11]. XOR low-3 bits with f(kt, q&1).
__device__ __forceinline__ int swz(int slot){
  return slot ^ ((slot >> 6) & 7) ^ (((slot >> 4) & 1) << 2);
}

#define KLIST(F) F(0) F(1) F(2) F(3) F(4) F(5) F(6) F(7) F(8) F(9) \
                 F(10) F(11) F(12) F(13) F(14) F(15) F(16) F(17) F(18) F(19)
#define SLIST(F) F(0) F(1) F(2) F(3) F(4)

// ---- pack weights into MFMA B-fragment order -------------------------------
// Wpack[ct][kt][lane][j]: ct in [0,256) covers gate-cols [ct*16, ct*16+16)
// (col = gate*1024 + n); element = W[k = kt*32 + (lane>>4)*8 + j][col = ct*16 + (lane&15)]
__global__ void prep_wpack(const float* __restrict__ Wfx, const float* __restrict__ Wix,
                           const float* __restrict__ Wgx, const float* __restrict__ Wox,
                           const float* __restrict__ Wfh, const float* __restrict__ Wih,
                           const float* __restrict__ Wgh, const float* __restrict__ Woh,
                           u16* __restrict__ Wpack){
  int id = blockIdx.x * 256 + threadIdx.x;    // [0, 655360)
  int lane = id & 63;
  int kt = (id >> 6) % NKT;
  int ct = id / (64 * NKT);
  int col = ct * 16 + (lane & 15);
  int g = col >> 10, n = col & 1023;
  int kbase = kt * 32 + (lane >> 4) * 8;
  const float* Wx = (g==0) ? Wfx : (g==1) ? Wix : (g==2) ? Wgx : Wox;
  const float* Wh = (g==0) ? Wfh : (g==1) ? Wih : (g==2) ? Wgh : Woh;
  u16x8 v;
  #pragma unroll
  for (int j = 0; j < 8; ++j){
    int k = kbase + j;
    float f = (k < DD) ? Wx[k * HH + n] : Wh[(k - DD) * HH + n];
    v[j] = f2bf(f);
  }
  *(u16x8*)(Wpack + (size_t)id * 8) = v;      // dst index == id (by construction)
}

// ---- transpose+cast x: xT[t][b][d] = bf16(x[b][t][d]) ----------------------
__global__ void prep_xT(const float* __restrict__ x, u16* __restrict__ xT){
  int id = blockIdx.x * 256 + threadIdx.x;    // [0, 1048576), 8 elems each
  int t = id >> 12;
  int b = (id >> 5) & 127;
  int d0 = (id & 31) * 8;
  const float* src = x + ((size_t)b * TT + t) * DD + d0;
  u16x8 v;
  #pragma unroll
  for (int j = 0; j < 8; ++j) v[j] = f2bf(src[j]);
  *(u16x8*)(xT + (size_t)id * 8) = v;
}

// ---- ALL 256 LSTM steps in one persistent cooperative kernel ---------------
__global__ __launch_bounds__(512, 2) void lstm_persist(
    const u16* __restrict__ xT,    // [T][B][D] bf16
    const u16* __restrict__ Wpack,
    u16* __restrict__ h0,          // [128][1024] bf16 (even-t input)
    u16* __restrict__ h1,          // [128][1024] bf16
    const float* __restrict__ bfv, const float* __restrict__ biv,
    const float* __restrict__ bgv, const float* __restrict__ bov,
    unsigned* __restrict__ barCnt){
  __shared__ u16x8 As4[NKT * 64];  // 40 KB: A tile in fragment order (swizzled)
  __shared__ float gLds[16][132];  // gate exchange (8.25 KB)
  __shared__ float pLds[16][132];  // K-half partial-sum exchange (8.25 KB)
  const int tid = threadIdx.x;
  const int bx = blockIdx.x >> 3;  // hidden-unit tile index  [0,32)
  const int by = blockIdx.x & 7;   // batch-row group         [0,8) == XCD
  const int n0 = bx * 32;
  const int m0 = by * 16;
  unsigned* const myCnt = barCnt + by * 32;  // group barrier counter (128B apart)

  const int w = tid >> 6, lane = tid & 63, cr = lane & 15, q4 = lane >> 4;
  const int g  = w & 3;            // gate
  const int kh = w >> 2;           // K-half: kt in [kh*20, kh*20+20)
  const int ktBeg = kh * KHT;

  // ---- load this wave's weights into 40 NAMED u16x8 (160 VGPRs), ONCE ----
  const size_t ct0 = (size_t)(g * 64 + bx * 2);  // 2 col-tiles of gate g
  const u16x8* Wp = (const u16x8*)Wpack;
  const u16x8* wq0 = Wp + ct0 * NKT * 64 + lane;
  const u16x8* wq1 = wq0 + NKT * 64;
#define DECLW(i) u16x8 w0_##i, w1_##i;
  KLIST(DECLW)
#define LOADW(i) w0_##i = wq0[(size_t)(ktBeg + (i)) * 64]; \
                 w1_##i = wq1[(size_t)(ktBeg + (i)) * 64];
  KLIST(LOADW)
  // Opaque pin: value now originates from asm -> cannot be rematerialized
  // from the (loop-invariant) load; allocator must keep it in VGPRs.
#define PINW(i) asm("" : "+v"(w0_##i), "+v"(w1_##i));
  KLIST(PINW)

  // bias (used by kh==0 waves in the combine)
  const float* bptr = (g==0) ? bfv : (g==1) ? biv : (g==2) ? bgv : bov;
  const float bias0 = bptr[n0 + cr], bias1 = bptr[n0 + 16 + cr];

  // ---- fixed per-thread staging geometry (named scalars, rule #20) ----
  // chunk ch -> row m = ch/160, k0 = (ch%160)*8 ; frag slot = kt*64 + 16*q + m
  unsigned isx = 0;
#define SGEOM(i) int so##i, sd##i; { int ch = tid + (i) * 512; \
    int m = ch / 160; int k0 = (ch - m * 160) * 8; \
    if (k0 < DD){ so##i = (m0 + m) * DD + k0; isx |= (1u << (i)); } \
    else        { so##i = (m0 + m) * HH + (k0 - DD); } \
    sd##i = swz((k0 >> 5) * 64 + 16 * ((k0 >> 3) & 3) + m); }
  SLIST(SGEOM)
#define STX(i) if ((isx >> (i)) & 1)   As4[sd##i] = *(const u16x8*)(xnext + so##i);
#define STH(i) if (!((isx >> (i)) & 1)) As4[sd##i] = *(const u16x8*)(hnext + so##i);

  // cell-update ownership is fixed: c lives in a register for all 256 steps
  const int crow = tid >> 5, cnn = tid & 31;
  const int gi = (m0 + crow) * HH + n0 + cnn;
  float cstate = 0.f;

  // prologue: stage x(t=0) and h(=0) into As4
  {
    const u16* xnext = xT;
    const u16* hnext = h0;
    SLIST(STX)
    SLIST(STH)
  }

  #pragma unroll 1
  for (int t = 0; t < TT; ++t){
    u16* hout = (t & 1) ? h0 : h1;
    __syncthreads();                 // sync0: A-tile fully staged

    f32x4 acc0 = {0.f, 0.f, 0.f, 0.f}, acc1 = {0.f, 0.f, 0.f, 0.f};
    u16x8 a0 = As4[swz(ktBeg * 64 + lane)];
    u16x8 a1 = As4[swz((ktBeg + 1) * 64 + lane)];
#define STEPK(i) { u16x8 ac = ((i) & 1) ? a1 : a0; \
    if ((i) + 2 < KHT){ \
      if ((i) & 1) a1 = As4[swz((ktBeg + (i) + 2) * 64 + lane)]; \
      else         a0 = As4[swz((ktBeg + (i) + 2) * 64 + lane)]; } \
    acc0 = __builtin_amdgcn_mfma_f32_16x16x32_bf16(__builtin_bit_cast(bf16x8, ac), \
             __builtin_bit_cast(bf16x8, w0_##i), acc0, 0, 0, 0); \
    acc1 = __builtin_amdgcn_mfma_f32_16x16x32_bf16(__builtin_bit_cast(bf16x8, ac), \
             __builtin_bit_cast(bf16x8, w1_##i), acc1, 0, 0, 0); }
    KLIST(STEPK)

    // combine K-halves (C/D layout: col=lane&15, row=q4*4+r)
    if (kh){
      #pragma unroll
      for (int r = 0; r < 4; ++r){
        pLds[q4 * 4 + r][g * 32 + cr]      = acc0[r];
        pLds[q4 * 4 + r][g * 32 + 16 + cr] = acc1[r];
      }
    }
    __syncthreads();                 // sync1: As4 reads done; pLds visible
    if (!kh){
      #pragma unroll
      for (int r = 0; r < 4; ++r){
        gLds[q4 * 4 + r][g * 32 + cr] =
            acc0[r] + pLds[q4 * 4 + r][g * 32 + cr] + bias0;
        gLds[q4 * 4 + r][g * 32 + 16 + cr] =
            acc1[r] + pLds[q4 * 4 + r][g * 32 + 16 + cr] + bias1;
      }
    }
    // stage next-step x early (h-independent): overlaps epilogue + barrier
    if (t + 1 < TT){
      const u16* xnext = xT + (size_t)(t + 1) * BB * DD;
      SLIST(STX)
    }
    __syncthreads();                 // sync2: gLds visible

    // fused LSTM cell update: 512 (row, hidden) units, 1 per thread
    {
      float fp = gLds[crow][cnn],      ip = gLds[crow][32 + cnn];
      float gp = gLds[crow][64 + cnn], op = gLds[crow][96 + cnn];
      float fs = sigm(fp);
      float is = sigm(ip);
      float gs = tanh_fast(gp);
      float os = sigm(op);
      cstate = gs * is + cstate * fs;
      hout[gi] = f2bf(tanh_fast(cstate) * os);
    }

    // ---- per-row-group barrier: per-WAVE arrival, all-wave acquire-poll ----
    // RELEASE add drains this wave's h stores first (vmcnt is wave-granular,
    // covering all 64 lanes). Target = 32 blocks x 8 waves = 256 arrivals.
    // The spin also subsumes the block-local barrier for the LDS recycle.
    if (t != TT - 1){
      if (lane == 0)
        __hip_atomic_fetch_add(myCnt, 1u, __ATOMIC_RELEASE,
                               __HIP_MEMORY_SCOPE_AGENT);
      const unsigned tgt = (unsigned)(t + 1) * 256u;
      while (__hip_atomic_load(myCnt, __ATOMIC_ACQUIRE,
                               __HIP_MEMORY_SCOPE_AGENT) < tgt)
        __builtin_amdgcn_s_sleep(1);
      // stage next-step h (written by peer blocks this step)
      const u16* hnext = hout;
      SLIST(STH)
    }
  }
}

// ---- out[b][c] = h_T[b] . Wph[:,c] + bp[c] ---------------------------------
__global__ void final_proj(const u16* __restrict__ h, const float* __restrict__ Wph,
                           const float* __restrict__ bp, float* __restrict__ out){
  __shared__ float red[10][256];
  int b = blockIdx.x, tid = threadIdx.x;
  float p[10];
  #pragma unroll
  for (int c = 0; c < 10; ++c) p[c] = 0.f;
  for (int k = tid; k < HH; k += 256){
    float hv = bf2f(h[b * HH + k]);
    const float* wr = Wph + (size_t)k * 10;
    #pragma unroll
    for (int c = 0; c < 10; ++c) p[c] += hv * wr[c];
  }
  #pragma unroll
  for (int c = 0; c < 10; ++c) red[c][tid] = p[c];
  __syncthreads();
  for (int s = 128; s > 0; s >>= 1){
    if (tid < s){
      #pragma unroll
      for (int c = 0; c < 10; ++c) red[c][tid] += red[c][tid + s];
    }
    __syncthreads();
  }
  if (tid < 10) out[b * 10 + tid] = red[tid][0] + bp[tid];
}

extern "C" void kernel_launch(void* const* d_in, const int* in_sizes, int n_in,
                              void* d_out, int out_size, void* d_ws, size_t ws_size,
                              hipStream_t stream){
  (void)in_sizes; (void)n_in; (void)out_size; (void)ws_size;
  const float* x   = (const float*)d_in[0];
  const float* Wfx = (const float*)d_in[1];
  const float* Wix = (const float*)d_in[2];
  const float* Wgx = (const float*)d_in[3];
  const float* Wox = (const float*)d_in[4];
  const float* Wfh = (const float*)d_in[5];
  const float* Wih = (const float*)d_in[6];
  const float* Wgh = (const float*)d_in[7];
  const float* Woh = (const float*)d_in[8];
  const float* bfv = (const float*)d_in[9];
  const float* biv = (const float*)d_in[10];
  const float* bgv = (const float*)d_in[11];
  const float* bov = (const float*)d_in[12];
  const float* Wph = (const float*)d_in[13];
  const float* bp  = (const float*)d_in[14];

  char* ws = (char*)d_ws;
  u16*  Wpack = (u16*)ws;                    // 10,485,760 B
  u16*  xT    = (u16*)(ws + 10485760);       // 16,777,216 B
  u16*  h0    = (u16*)(ws + 27262976);       //    262,144 B
  u16*  h1    = (u16*)(ws + 27525120);       //    262,144 B
  unsigned* barCnt = (unsigned*)(ws + 27787264);  // 1,024 B

  prep_wpack<<<2560, 256, 0, stream>>>(Wfx, Wix, Wgx, Wox, Wfh, Wih, Wgh, Woh, Wpack);
  prep_xT<<<4096, 256, 0, stream>>>(x, xT);
  hipMemsetAsync(h0, 0, 262144, stream);
  hipMemsetAsync(barCnt, 0, 1024, stream);

  void* args[] = {(void*)&xT, (void*)&Wpack, (void*)&h0, (void*)&h1,
                  (void*)&bfv, (void*)&biv, (void*)&bgv, (void*)&bov,
                  (void*)&barCnt};
  hipLaunchCooperativeKernel((const void*)lstm_persist, dim3(256), dim3(512),
                             args, 0, stream);

  // t=255 (odd) wrote h0 -> final hidden state lives in h0
  final_proj<<<128, 256, 0, stream>>>(h0, Wph, bp, (float*)d_out);
}

// Round 8
// 1981.420 us; speedup vs baseline: 8.5040x; 8.5040x over previous
//
#include <hip/hip_runtime.h>
#include <math.h>

// LSTM: B=128, T=256, D=256, H=1024, C=10
// Round 9: diagnose-and-protect.
//   R7/R8 post-mortem: identical absmax 7.476807e-03 across two DIFFERENT
//   kernels == max|ref| vs all-zero output => h stayed memset-zero =>
//   lstm_persist never ran: hipLaunchCooperativeKernel was REFUSED (error
//   never checked -> silent no-op; graph stayed valid, which R7/R8 proved).
//   Root cause: register-resident weight configs sit at EXACTLY the
//   co-residency limit (160 weight VGPRs/wave => grid == occupancy bound);
//   R3/R6 launched because remat kept VGPR=112 (2x margin).
//   This round:
//   - Occupancy-gate (host query, capture-safe) + launch-error check.
//   - On refusal: proven Round-1 per-step path (1983us) as fallback.
//     cbuf (fallback) aliases barCnt (coop) - paths mutually exclusive.
//   - Cooperative kernel = R8's unchanged (demand ~225 < 256 cap).
//   Outcomes: 256x lstm_step dispatches @~1983us => refusal confirmed;
//   1x lstm_persist @~1000-1300us pass => resident weights work;
//   lstm_persist fail => in-kernel bug, abandon persistence.
// Workspace layout:
//   [0)          Wpack  bf16  10,485,760 B
//   [10485760)   xT     bf16  16,777,216 B   ([T][B][D], x transposed+cast)
//   [27262976)   h0     bf16     262,144 B
//   [27525120)   h1     bf16     262,144 B
//   [27787264)   cbuf   fp32     524,288 B   (fallback c-state)  } aliased
//   [27787264)   barCnt u32        1,024 B   (coop barrier)      } aliased

#define BB 128
#define TT 256
#define DD 256
#define HH 1024
#define NKT 40   // 1280 / 32 k-tiles
#define KHT 20   // k-tiles per K-half wave (fallback kernel)
#define PF 4     // fallback prefetch depth

typedef __bf16 bf16x8 __attribute__((ext_vector_type(8)));
typedef float  f32x4  __attribute__((ext_vector_type(4)));
typedef unsigned short u16;
typedef u16 u16x8 __attribute__((ext_vector_type(8)));

__device__ __forceinline__ u16 f2bf(float f){
  unsigned u = __builtin_bit_cast(unsigned, f);
  u += 0x7fffu + ((u >> 16) & 1u);            // round-to-nearest-even
  return (u16)(u >> 16);
}
__device__ __forceinline__ float bf2f(u16 b){
  unsigned u = ((unsigned)b) << 16;
  return __builtin_bit_cast(float, u);
}
__device__ __forceinline__ float sigm(float x){
  return 1.f / (1.f + __expf(-x));
}
__device__ __forceinline__ float tanh_fast(float x){
  return 2.f / (1.f + __expf(-2.f * x)) - 1.f;
}
// LDS A-tile swizzle (persist kernel): breaks staging-write bank conflict.
__device__ __forceinline__ int swz(int slot){
  return slot ^ ((slot >> 6) & 7) ^ (((slot >> 4) & 1) << 2);
}

#define KLIST40(F) F(0) F(1) F(2) F(3) F(4) F(5) F(6) F(7) F(8) F(9) \
  F(10) F(11) F(12) F(13) F(14) F(15) F(16) F(17) F(18) F(19) \
  F(20) F(21) F(22) F(23) F(24) F(25) F(26) F(27) F(28) F(29) \
  F(30) F(31) F(32) F(33) F(34) F(35) F(36) F(37) F(38) F(39)
#define SLIST10(F) F(0) F(1) F(2) F(3) F(4) F(5) F(6) F(7) F(8) F(9)

// ---- pack weights into MFMA B-fragment order -------------------------------
__global__ void prep_wpack(const float* __restrict__ Wfx, const float* __restrict__ Wix,
                           const float* __restrict__ Wgx, const float* __restrict__ Wox,
                           const float* __restrict__ Wfh, const float* __restrict__ Wih,
                           const float* __restrict__ Wgh, const float* __restrict__ Woh,
                           u16* __restrict__ Wpack){
  int id = blockIdx.x * 256 + threadIdx.x;    // [0, 655360)
  int lane = id & 63;
  int kt = (id >> 6) % NKT;
  int ct = id / (64 * NKT);
  int col = ct * 16 + (lane & 15);
  int g = col >> 10, n = col & 1023;
  int kbase = kt * 32 + (lane >> 4) * 8;
  const float* Wx = (g==0) ? Wfx : (g==1) ? Wix : (g==2) ? Wgx : Wox;
  const float* Wh = (g==0) ? Wfh : (g==1) ? Wih : (g==2) ? Wgh : Woh;
  u16x8 v;
  #pragma unroll
  for (int j = 0; j < 8; ++j){
    int k = kbase + j;
    float f = (k < DD) ? Wx[k * HH + n] : Wh[(k - DD) * HH + n];
    v[j] = f2bf(f);
  }
  *(u16x8*)(Wpack + (size_t)id * 8) = v;
}

// ---- transpose+cast x: xT[t][b][d] = bf16(x[b][t][d]) ----------------------
__global__ void prep_xT(const float* __restrict__ x, u16* __restrict__ xT){
  int id = blockIdx.x * 256 + threadIdx.x;    // [0, 1048576), 8 elems each
  int t = id >> 12;
  int b = (id >> 5) & 127;
  int d0 = (id & 31) * 8;
  const float* src = x + ((size_t)b * TT + t) * DD + d0;
  u16x8 v;
  #pragma unroll
  for (int j = 0; j < 8; ++j) v[j] = f2bf(src[j]);
  *(u16x8*)(xT + (size_t)id * 8) = v;
}

// ---- persistent kernel (R8, unchanged): all 256 steps, resident weights ----
__global__ __launch_bounds__(256, 2) void lstm_persist(
    const u16* __restrict__ xT, const u16* __restrict__ Wpack,
    u16* __restrict__ h0, u16* __restrict__ h1,
    const float* __restrict__ bfv, const float* __restrict__ biv,
    const float* __restrict__ bgv, const float* __restrict__ bov,
    unsigned* __restrict__ barCnt){
  __shared__ u16x8 As4[NKT * 64];
  __shared__ float gLds[16][68];
  const int tid = threadIdx.x;
  const int bx = blockIdx.x >> 3;
  const int by = blockIdx.x & 7;
  const int n0 = bx * 16;
  const int m0 = by * 16;
  unsigned* const myCnt = barCnt + by * 32;

  const int g = tid >> 6;
  const int lane = tid & 63, cr = lane & 15, q4 = lane >> 4;

  const u16x8* wq = (const u16x8*)Wpack + (size_t)(g * 64 + bx) * NKT * 64 + lane;
#define DECLW(i) u16x8 w_##i;
  KLIST40(DECLW)
#define LOADW(i) w_##i = wq[(size_t)(i) * 64];
  KLIST40(LOADW)
#define PINW(i) asm("" : "+v"(w_##i));
  KLIST40(PINW)

  const float* bptr = (g==0) ? bfv : (g==1) ? biv : (g==2) ? bgv : bov;
  const float bias = bptr[n0 + cr];

  unsigned isx = 0;
#define SGEOM(i) int so##i, sd##i; { int ch = tid + (i) * 256; \
    int m = ch / 160; int k0 = (ch - m * 160) * 8; \
    if (k0 < DD){ so##i = (m0 + m) * DD + k0; isx |= (1u << (i)); } \
    else        { so##i = (m0 + m) * HH + (k0 - DD); } \
    sd##i = swz((k0 >> 5) * 64 + 16 * ((k0 >> 3) & 3) + m); }
  SLIST10(SGEOM)
#define STX(i) if ((isx >> (i)) & 1)   As4[sd##i] = *(const u16x8*)(xnext + so##i);
#define STH(i) if (!((isx >> (i)) & 1)) As4[sd##i] = *(const u16x8*)(hnext + so##i);

  const int crow = tid >> 4, cnn = tid & 15;
  const int gi = (m0 + crow) * HH + n0 + cnn;
  float cstate = 0.f;

  {
    const u16* xnext = xT;
    const u16* hnext = h0;
    SLIST10(STX)
    SLIST10(STH)
  }

  #pragma unroll 1
  for (int t = 0; t < TT; ++t){
    u16* hout = (t & 1) ? h0 : h1;
    __syncthreads();

    f32x4 accA = {0.f, 0.f, 0.f, 0.f}, accB = {0.f, 0.f, 0.f, 0.f};
    u16x8 a0 = As4[swz(0 * 64 + lane)];
    u16x8 a1 = As4[swz(1 * 64 + lane)];
    u16x8 a2 = As4[swz(2 * 64 + lane)];
    u16x8 a3 = As4[swz(3 * 64 + lane)];
#define AS(i) (((i)&3)==0 ? a0 : ((i)&3)==1 ? a1 : ((i)&3)==2 ? a2 : a3)
#define STEPK(i) { u16x8 ac = AS(i); \
    if ((i) + 4 < NKT){ int ld = swz(((i) + 4) * 64 + lane); \
      if (((i)&3)==0) a0 = As4[ld]; else if (((i)&3)==1) a1 = As4[ld]; \
      else if (((i)&3)==2) a2 = As4[ld]; else a3 = As4[ld]; } \
    if ((i) & 1) accB = __builtin_amdgcn_mfma_f32_16x16x32_bf16( \
        __builtin_bit_cast(bf16x8, ac), __builtin_bit_cast(bf16x8, w_##i), accB, 0, 0, 0); \
    else accA = __builtin_amdgcn_mfma_f32_16x16x32_bf16( \
        __builtin_bit_cast(bf16x8, ac), __builtin_bit_cast(bf16x8, w_##i), accA, 0, 0, 0); }
    KLIST40(STEPK)

    #pragma unroll
    for (int r = 0; r < 4; ++r)
      gLds[q4 * 4 + r][g * 16 + cr] = accA[r] + accB[r] + bias;
    __syncthreads();

    if (t + 1 < TT){
      const u16* xnext = xT + (size_t)(t + 1) * BB * DD;
      SLIST10(STX)
    }

    {
      float fp = gLds[crow][cnn],      ip = gLds[crow][16 + cnn];
      float gp = gLds[crow][32 + cnn], op = gLds[crow][48 + cnn];
      cstate = tanh_fast(gp) * sigm(ip) + cstate * sigm(fp);
      hout[gi] = f2bf(tanh_fast(cstate) * sigm(op));
    }

    if (t != TT - 1){
      __syncthreads();
      if (tid == 0){
        __threadfence();
        __hip_atomic_fetch_add(myCnt, 1u, __ATOMIC_RELAXED,
                               __HIP_MEMORY_SCOPE_AGENT);
        const unsigned tgt = (unsigned)(t + 1) * 64u;   // 64 blocks/group
        while (__hip_atomic_load(myCnt, __ATOMIC_RELAXED,
                                 __HIP_MEMORY_SCOPE_AGENT) < tgt)
          __builtin_amdgcn_s_sleep(2);
        __threadfence();
      }
      __syncthreads();
      const u16* hnext = hout;
      SLIST10(STH)
    }
  }
}

// ---- FALLBACK: Round-1 per-step kernel (proven, 1983us total) --------------
__global__ __launch_bounds__(512) void lstm_step(
    const u16* __restrict__ xTt, const u16* __restrict__ Wpack,
    const u16* __restrict__ hin, u16* __restrict__ hout,
    float* __restrict__ cbuf,
    const float* __restrict__ bfv, const float* __restrict__ biv,
    const float* __restrict__ bgv, const float* __restrict__ bov){
  __shared__ u16x8 As4[NKT * 64];
  __shared__ float gLds[16][132];
  __shared__ float pLds[16][132];
  const int tid = threadIdx.x;
  const int n0 = blockIdx.x * 32;
  const int m0 = blockIdx.y * 16;

  const int w = tid >> 6, lane = tid & 63, cr = lane & 15, q4 = lane >> 4;
  const int g  = w & 3;
  const int kh = w >> 2;
  const int ktBeg = kh * KHT;

  const size_t ct0 = (size_t)(g * 64 + blockIdx.x * 2);
  const u16x8* Wp = (const u16x8*)Wpack;
  const u16x8* wq0 = Wp + ct0 * NKT * 64 + lane;
  const u16x8* wq1 = wq0 + NKT * 64;

  u16x8 aP[PF], b0P[PF], b1P[PF];
  #pragma unroll
  for (int i = 0; i < PF; ++i){
    b0P[i] = wq0[(size_t)(ktBeg + i) * 64];
    b1P[i] = wq1[(size_t)(ktBeg + i) * 64];
  }

  #pragma unroll
  for (int it = 0; it < 5; ++it){
    int ch = tid + it * 512;
    int m = ch / 160;
    int k0 = (ch - m * 160) * 8;
    const u16* src = (k0 < DD) ? (xTt + (m0 + m) * DD + k0)
                               : (hin + (m0 + m) * HH + (k0 - DD));
    u16x8 val = *(const u16x8*)src;
    int kt = k0 >> 5, q = (k0 >> 3) & 3;
    As4[kt * 64 + 16 * q + m] = val;
  }
  __syncthreads();

  #pragma unroll
  for (int i = 0; i < PF; ++i) aP[i] = As4[(ktBeg + i) * 64 + lane];

  f32x4 acc0 = {0.f, 0.f, 0.f, 0.f}, acc1 = {0.f, 0.f, 0.f, 0.f};
  #pragma unroll
  for (int kt = 0; kt < KHT; ++kt){
    const int slot = kt & (PF - 1);
    u16x8 ac = aP[slot], b0 = b0P[slot], b1 = b1P[slot];
    if (kt + PF < KHT){
      aP[slot]  = As4[(ktBeg + kt + PF) * 64 + lane];
      b0P[slot] = wq0[(size_t)(ktBeg + kt + PF) * 64];
      b1P[slot] = wq1[(size_t)(ktBeg + kt + PF) * 64];
    }
    acc0 = __builtin_amdgcn_mfma_f32_16x16x32_bf16(__builtin_bit_cast(bf16x8, ac),
             __builtin_bit_cast(bf16x8, b0), acc0, 0, 0, 0);
    acc1 = __builtin_amdgcn_mfma_f32_16x16x32_bf16(__builtin_bit_cast(bf16x8, ac),
             __builtin_bit_cast(bf16x8, b1), acc1, 0, 0, 0);
  }

  if (kh){
    #pragma unroll
    for (int r = 0; r < 4; ++r){
      pLds[q4 * 4 + r][g * 32 + cr]      = acc0[r];
      pLds[q4 * 4 + r][g * 32 + 16 + cr] = acc1[r];
    }
  }
  __syncthreads();
  if (!kh){
    const float* bptr = (g==0) ? bfv : (g==1) ? biv : (g==2) ? bgv : bov;
    float bias0 = bptr[n0 + cr], bias1 = bptr[n0 + 16 + cr];
    #pragma unroll
    for (int r = 0; r < 4; ++r){
      gLds[q4 * 4 + r][g * 32 + cr] =
          acc0[r] + pLds[q4 * 4 + r][g * 32 + cr] + bias0;
      gLds[q4 * 4 + r][g * 32 + 16 + cr] =
          acc1[r] + pLds[q4 * 4 + r][g * 32 + 16 + cr] + bias1;
    }
  }
  __syncthreads();

  {
    int row = tid >> 5, nn = tid & 31;
    float fp = gLds[row][nn],      ip = gLds[row][32 + nn];
    float gp = gLds[row][64 + nn], op = gLds[row][96 + nn];
    float fs = 1.f / (1.f + expf(-fp));
    float is = 1.f / (1.f + expf(-ip));
    float gs = tanhf(gp);
    float os = 1.f / (1.f + expf(-op));
    int gi = (m0 + row) * HH + n0 + nn;
    float cn = gs * is + cbuf[gi] * fs;
    cbuf[gi] = cn;
    hout[gi] = f2bf(tanhf(cn) * os);
  }
}

// ---- out[b][c] = h_T[b] . Wph[:,c] + bp[c] ---------------------------------
__global__ void final_proj(const u16* __restrict__ h, const float* __restrict__ Wph,
                           const float* __restrict__ bp, float* __restrict__ out){
  __shared__ float red[10][256];
  int b = blockIdx.x, tid = threadIdx.x;
  float p[10];
  #pragma unroll
  for (int c = 0; c < 10; ++c) p[c] = 0.f;
  for (int k = tid; k < HH; k += 256){
    float hv = bf2f(h[b * HH + k]);
    const float* wr = Wph + (size_t)k * 10;
    #pragma unroll
    for (int c = 0; c < 10; ++c) p[c] += hv * wr[c];
  }
  #pragma unroll
  for (int c = 0; c < 10; ++c) red[c][tid] = p[c];
  __syncthreads();
  for (int s = 128; s > 0; s >>= 1){
    if (tid < s){
      #pragma unroll
      for (int c = 0; c < 10; ++c) red[c][tid] += red[c][tid + s];
    }
    __syncthreads();
  }
  if (tid < 10) out[b * 10 + tid] = red[tid][0] + bp[tid];
}

extern "C" void kernel_launch(void* const* d_in, const int* in_sizes, int n_in,
                              void* d_out, int out_size, void* d_ws, size_t ws_size,
                              hipStream_t stream){
  (void)in_sizes; (void)n_in; (void)out_size; (void)ws_size;
  const float* x   = (const float*)d_in[0];
  const float* Wfx = (const float*)d_in[1];
  const float* Wix = (const float*)d_in[2];
  const float* Wgx = (const float*)d_in[3];
  const float* Wox = (const float*)d_in[4];
  const float* Wfh = (const float*)d_in[5];
  const float* Wih = (const float*)d_in[6];
  const float* Wgh = (const float*)d_in[7];
  const float* Woh = (const float*)d_in[8];
  const float* bfv = (const float*)d_in[9];
  const float* biv = (const float*)d_in[10];
  const float* bgv = (const float*)d_in[11];
  const float* bov = (const float*)d_in[12];
  const float* Wph = (const float*)d_in[13];
  const float* bp  = (const float*)d_in[14];

  char* ws = (char*)d_ws;
  u16*  Wpack = (u16*)ws;                         // 10,485,760 B
  u16*  xT    = (u16*)(ws + 10485760);            // 16,777,216 B
  u16*  h0    = (u16*)(ws + 27262976);            //    262,144 B
  u16*  h1    = (u16*)(ws + 27525120);            //    262,144 B
  float* cb   = (float*)(ws + 27787264);          //    524,288 B (fallback)
  unsigned* barCnt = (unsigned*)(ws + 27787264);  //      1,024 B (coop; aliased)

  prep_wpack<<<2560, 256, 0, stream>>>(Wfx, Wix, Wgx, Wox, Wfh, Wih, Wgh, Woh, Wpack);
  prep_xT<<<4096, 256, 0, stream>>>(x, xT);
  hipMemsetAsync(h0, 0, 262144, stream);

  // ---- gate: can 512 blocks of lstm_persist be co-resident? ----
  int nb = 0;
  hipError_t qe = hipOccupancyMaxActiveBlocksPerMultiprocessor(
      &nb, (const void*)lstm_persist, 256, 0);
  hipError_t ce = hipErrorUnknown;
  if (qe == hipSuccess && nb >= 2){
    hipMemsetAsync(barCnt, 0, 1024, stream);
    void* args[] = {(void*)&xT, (void*)&Wpack, (void*)&h0, (void*)&h1,
                    (void*)&bfv, (void*)&biv, (void*)&bgv, (void*)&bov,
                    (void*)&barCnt};
    ce = hipLaunchCooperativeKernel((const void*)lstm_persist, dim3(512),
                                    dim3(256), args, 0, stream);
  }
  if (ce != hipSuccess){
    // ---- proven per-step fallback (Round-1 path, 1983 us) ----
    hipMemsetAsync(cb, 0, 524288, stream);
    for (int t = 0; t < TT; ++t){
      const u16* hin  = (t & 1) ? h1 : h0;
      u16*       hout = (t & 1) ? h0 : h1;
      lstm_step<<<dim3(32, 8), 512, 0, stream>>>(xT + (size_t)t * BB * DD, Wpack,
                                                 hin, hout, cb, bfv, biv, bgv, bov);
    }
  }

  // t=255 (odd) wrote h0 in both paths -> final hidden state lives in h0
  final_proj<<<128, 256, 0, stream>>>(h0, Wph, bp, (float*)d_out);
}